// Round 8
// baseline (13134.462 us; speedup 1.0000x reference)
//
#include <hip/hip_runtime.h>
#include <hip/hip_bf16.h>
#include <stdint.h>

// ResRnn persistent kernel for MI355X — round 8.
// Weight-stationary 2D partition: 8 row-groups x 32 col-blocks = 256 WGs (1/CU);
// W1/W2 32x1024 bf16 slices LDS-resident (128 KiB), XOR-swizzled. Coherence = the
// proven protocol: sc0 sc1 write-through stores, sc0 sc1 loads, relaxed agent atomics.
// NEW: two interleaved half-batch chains (rows 0-15 / 16-31 of each group) with
// separate flag sets. Schedule P1A | wait sB | P1B | wait hA | P2A | wait hB | P2B |
// wait sA' — every exchange wait is preceded by a compute slot of the other chain,
// hiding the ~4-roundtrip exchange latency that round 7 showed dominates (93% stall).
// Each slot: 16-row tile, waves k-split (kh=wv>>1 covers K=512) + LDS merge-reduce.

#define NSTEP  1024
#define BATCH  256
#define INSZ   64
#define SSZ    1024

#define GROUPS 8
#define CBLKS  32
#define RPG    32   // rows per group
#define RPH    16   // rows per half-chain
#define CPB    32   // cols per block
#define FPAD   16   // flag padding (64 B per flag)
#define TSTR   36   // transpose-tile row stride in f32

typedef __bf16   bf16x8 __attribute__((ext_vector_type(8)));
typedef float    f32x4  __attribute__((ext_vector_type(4)));
typedef unsigned u32x2  __attribute__((ext_vector_type(2)));

#define SCHED_FENCE() __builtin_amdgcn_sched_barrier(0)
#define WAITN(n) do { asm volatile("s_waitcnt vmcnt(" #n ")" ::: "memory"); SCHED_FENCE(); } while (0)

// 8 A-fragment loads (16B each, stride 64B = one MFMA k-step), L3-coherent.
__device__ __forceinline__ void issue8(const char* p,
    bf16x8& r0, bf16x8& r1, bf16x8& r2, bf16x8& r3,
    bf16x8& r4, bf16x8& r5, bf16x8& r6, bf16x8& r7)
{
    asm volatile(
        "global_load_dwordx4 %0, %8, off sc0 sc1\n\t"
        "global_load_dwordx4 %1, %8, off offset:64 sc0 sc1\n\t"
        "global_load_dwordx4 %2, %8, off offset:128 sc0 sc1\n\t"
        "global_load_dwordx4 %3, %8, off offset:192 sc0 sc1\n\t"
        "global_load_dwordx4 %4, %8, off offset:256 sc0 sc1\n\t"
        "global_load_dwordx4 %5, %8, off offset:320 sc0 sc1\n\t"
        "global_load_dwordx4 %6, %8, off offset:384 sc0 sc1\n\t"
        "global_load_dwordx4 %7, %8, off offset:448 sc0 sc1"
        : "=&v"(r0), "=&v"(r1), "=&v"(r2), "=&v"(r3),
          "=&v"(r4), "=&v"(r5), "=&v"(r6), "=&v"(r7)
        : "v"(p) : "memory");
}

// Issue-only prefetch of 4 scattered coherent dwords (completed by a later vmcnt(0)).
__device__ __forceinline__ void issue4f(const float* p0, const float* p1,
                                        const float* p2, const float* p3,
                                        float& r0, float& r1, float& r2, float& r3)
{
    asm volatile(
        "global_load_dword %0, %4, off sc0 sc1\n\t"
        "global_load_dword %1, %5, off sc0 sc1\n\t"
        "global_load_dword %2, %6, off sc0 sc1\n\t"
        "global_load_dword %3, %7, off sc0 sc1"
        : "=&v"(r0), "=&v"(r1), "=&v"(r2), "=&v"(r3)
        : "v"(p0), "v"(p1), "v"(p2), "v"(p3)
        : "memory");
}

__device__ __forceinline__ void st_coh_u16(void* p, unsigned short v) {
    asm volatile("global_store_short %0, %1, off sc0 sc1" :: "v"(p), "v"(v) : "memory");
}
__device__ __forceinline__ void st_coh_f32(void* p, float v) {
    asm volatile("global_store_dword %0, %1, off sc0 sc1" :: "v"(p), "v"(v) : "memory");
}
__device__ __forceinline__ void st_coh_b64(void* p, u32x2 v) {
    asm volatile("global_store_dwordx2 %0, %1, off sc0 sc1" :: "v"(p), "v"(v) : "memory");
}
__device__ __forceinline__ void st_coh_b128(void* p, f32x4 v) {
    asm volatile("global_store_dwordx4 %0, %1, off sc0 sc1" :: "v"(p), "v"(v) : "memory");
}

__device__ __forceinline__ u32x2 pack_bf16x4(f32x4 f) {
    unsigned a = __builtin_bit_cast(unsigned short, (__bf16)f[0]);
    unsigned b = __builtin_bit_cast(unsigned short, (__bf16)f[1]);
    unsigned c = __builtin_bit_cast(unsigned short, (__bf16)f[2]);
    unsigned d = __builtin_bit_cast(unsigned short, (__bf16)f[3]);
    u32x2 r; r[0] = a | (b << 16); r[1] = c | (d << 16);
    return r;
}

// Publish: drain all our coherent stores to the coherence point, then set our flag.
__device__ __forceinline__ void publish_flags(unsigned* fl, int c, unsigned e, int tid)
{
    asm volatile("s_waitcnt vmcnt(0)" ::: "memory");
    __syncthreads();
    if (tid == 0)
        __hip_atomic_store(&fl[c * FPAD], e, __ATOMIC_RELAXED,
                           __HIP_MEMORY_SCOPE_AGENT);
}

// Wait: wave 0 polls the 32 peer flags of one chain; epochs strictly increasing;
// signed-diff compare tolerates 0xAA poison; bail-out prevents harness hangs.
__device__ __forceinline__ void wait_flags(unsigned* fl, unsigned e, int tid)
{
    if (tid < 64) {
        uint64_t t0 = __builtin_amdgcn_s_memrealtime();
        for (;;) {
            unsigned v = e;
            if (tid < CBLKS)
                v = __hip_atomic_load(&fl[tid * FPAD], __ATOMIC_RELAXED,
                                      __HIP_MEMORY_SCOPE_AGENT);
            if (!__any((int)(v - e) < 0)) break;
            if (__builtin_amdgcn_s_memrealtime() - t0 > 400000ull) break; // ~4ms bail
        }
    }
    __syncthreads();
}

// 8 MFMAs for k-steps BASE..BASE+7 within this wave's K-half (kboff = kh*1024 bytes).
#define MFMA8(BASE, A0, A1, A2, A3, A4, A5, A6, A7)                                        \
    do {                                                                                   \
        acc0 = __builtin_amdgcn_mfma_f32_16x16x32_bf16(A0,                                 \
            *reinterpret_cast<const bf16x8*>(Bw + ((kboff + ((BASE) + 0) * 64 + kbyte) ^ bswz)), acc0, 0, 0, 0); \
        acc1 = __builtin_amdgcn_mfma_f32_16x16x32_bf16(A1,                                 \
            *reinterpret_cast<const bf16x8*>(Bw + ((kboff + ((BASE) + 1) * 64 + kbyte) ^ bswz)), acc1, 0, 0, 0); \
        acc2 = __builtin_amdgcn_mfma_f32_16x16x32_bf16(A2,                                 \
            *reinterpret_cast<const bf16x8*>(Bw + ((kboff + ((BASE) + 2) * 64 + kbyte) ^ bswz)), acc2, 0, 0, 0); \
        acc3 = __builtin_amdgcn_mfma_f32_16x16x32_bf16(A3,                                 \
            *reinterpret_cast<const bf16x8*>(Bw + ((kboff + ((BASE) + 3) * 64 + kbyte) ^ bswz)), acc3, 0, 0, 0); \
        acc0 = __builtin_amdgcn_mfma_f32_16x16x32_bf16(A4,                                 \
            *reinterpret_cast<const bf16x8*>(Bw + ((kboff + ((BASE) + 4) * 64 + kbyte) ^ bswz)), acc0, 0, 0, 0); \
        acc1 = __builtin_amdgcn_mfma_f32_16x16x32_bf16(A5,                                 \
            *reinterpret_cast<const bf16x8*>(Bw + ((kboff + ((BASE) + 5) * 64 + kbyte) ^ bswz)), acc1, 0, 0, 0); \
        acc2 = __builtin_amdgcn_mfma_f32_16x16x32_bf16(A6,                                 \
            *reinterpret_cast<const bf16x8*>(Bw + ((kboff + ((BASE) + 6) * 64 + kbyte) ^ bswz)), acc2, 0, 0, 0); \
        acc3 = __builtin_amdgcn_mfma_f32_16x16x32_bf16(A7,                                 \
            *reinterpret_cast<const bf16x8*>(Bw + ((kboff + ((BASE) + 7) * 64 + kbyte) ^ bswz)), acc3, 0, 0, 0); \
    } while (0)

// One 16x16 partial tile over this wave's K-half (512): 16 A-loads issued upfront,
// drained vmcnt(8)/vmcnt(0). (Outstanding prefetches issued earlier are older, so
// WAITN(8) over-waits them harmlessly.)
__device__ __forceinline__ f32x4 phase_mm_half(const char* Ab, const char* Bw,
                                               int kbyte, int bswz, int kboff)
{
    f32x4 acc0 = {0.f, 0.f, 0.f, 0.f}, acc1 = acc0, acc2 = acc0, acc3 = acc0;
    bf16x8 a0, a1, a2, a3, a4, a5, a6, a7;
    bf16x8 b0, b1, b2, b3, b4, b5, b6, b7;
    issue8(Ab,       a0, a1, a2, a3, a4, a5, a6, a7);
    issue8(Ab + 512, b0, b1, b2, b3, b4, b5, b6, b7);
    WAITN(8); MFMA8(0, a0, a1, a2, a3, a4, a5, a6, a7);
    WAITN(0); MFMA8(8, b0, b1, b2, b3, b4, b5, b6, b7);
    return (acc0 + acc1) + (acc2 + acc3);
}

extern "C" __global__ void __launch_bounds__(256, 1)
resrnn_kernel(const float* __restrict__ x,  const float* __restrict__ W1,
              const float* __restrict__ b1, const float* __restrict__ W2,
              const float* __restrict__ b2,
              __bf16* sBuf, __bf16* hBuf, float* sf32, unsigned* flags,
              float* __restrict__ dout)
{
    extern __shared__ char smem[];
    char*  W1s = smem;                     // 64 KiB
    char*  W2s = smem + 65536;             // 64 KiB
    float* T   = (float*)(smem + 131072);  // 16 x TSTR f32 merge/transpose scratch

    const int tid = threadIdx.x;
    const int bid = blockIdx.x;
    const int g   = bid & 7;
    const int c   = bid >> 3;
    const int rb  = g * RPG;
    const int cb  = c * CPB;

    // ---- stage weight slices to LDS (fp32 -> bf16, XOR-swizzle by col) ----
    {
        const int lcw = tid >> 3;
        const int seg = (tid & 7) * 128;
        const int sw  = (lcw & 7) << 4;
        const float* w1p = W1 + (size_t)(cb + lcw) * SSZ + seg;
        const float* w2p = W2 + (size_t)(cb + lcw) * SSZ + seg;
        char* d1 = W1s + lcw * 2048;
        char* d2 = W2s + lcw * 2048;
        #pragma unroll 4
        for (int kk = 0; kk < 16; ++kk) {
            const int kb = (seg + kk * 8) * 2;
            f32x4 f0 = reinterpret_cast<const f32x4*>(w1p)[kk * 2 + 0];
            f32x4 f1 = reinterpret_cast<const f32x4*>(w1p)[kk * 2 + 1];
            bf16x8 v;
            v[0] = (__bf16)f0[0]; v[1] = (__bf16)f0[1]; v[2] = (__bf16)f0[2]; v[3] = (__bf16)f0[3];
            v[4] = (__bf16)f1[0]; v[5] = (__bf16)f1[1]; v[6] = (__bf16)f1[2]; v[7] = (__bf16)f1[3];
            *reinterpret_cast<bf16x8*>(d1 + (kb ^ sw)) = v;
            f0 = reinterpret_cast<const f32x4*>(w2p)[kk * 2 + 0];
            f1 = reinterpret_cast<const f32x4*>(w2p)[kk * 2 + 1];
            v[0] = (__bf16)f0[0]; v[1] = (__bf16)f0[1]; v[2] = (__bf16)f0[2]; v[3] = (__bf16)f0[3];
            v[4] = (__bf16)f1[0]; v[5] = (__bf16)f1[1]; v[6] = (__bf16)f1[2]; v[7] = (__bf16)f1[3];
            *reinterpret_cast<bf16x8*>(d2 + (kb ^ sw)) = v;
        }
    }

    // ---- init: sBuf = [x_0 | 0] (bf16), sf32[buf0] = 0, coherent stores ----
    {
        const int e0  = tid * 4;
        const int row = rb + (e0 >> 5);
        const int col = cb + (e0 & 31);
        float* sp32 = sf32 + (size_t)row * SSZ + col;
        st_coh_f32(sp32 + 0, 0.f); st_coh_f32(sp32 + 1, 0.f);
        st_coh_f32(sp32 + 2, 0.f); st_coh_f32(sp32 + 3, 0.f);
        __bf16* sp = sBuf + (size_t)row * SSZ + col;
        if (c < 2) {
            const float* xp = x + (size_t)row * INSZ + col;
            #pragma unroll
            for (int i = 0; i < 4; ++i)
                st_coh_u16(sp + i, __builtin_bit_cast(unsigned short, (__bf16)xp[i]));
        } else {
            #pragma unroll
            for (int i = 0; i < 4; ++i)
                st_coh_u16(sp + i, __builtin_bit_cast(unsigned short, (__bf16)0.f));
        }
    }

    unsigned* flA = flags + (size_t)g * (CBLKS * FPAD);
    unsigned* flB = flags + (size_t)(8 + g) * (CBLKS * FPAD);

    // init publish epoch 1 on both chains, wait both
    asm volatile("s_waitcnt vmcnt(0)" ::: "memory");
    __syncthreads();
    if (tid == 0) {
        __hip_atomic_store(&flA[c * FPAD], 1u, __ATOMIC_RELAXED, __HIP_MEMORY_SCOPE_AGENT);
        __hip_atomic_store(&flB[c * FPAD], 1u, __ATOMIC_RELAXED, __HIP_MEMORY_SCOPE_AGENT);
    }
    wait_flags(flA, 1u, tid);
    wait_flags(flB, 1u, tid);

    // ---- per-thread geometry ----
    const int lane  = tid & 63;
    const int wv    = tid >> 6;
    const int kh    = wv >> 1;                       // K-half  (0: k<512, 1: k>=512)
    const int nh    = wv & 1;                        // col half of the 32-col tile
    const int kboff = kh * 1024;                     // byte offset of K-half
    const int kgrp  = lane >> 4;
    const int kbyte = kgrp * 16;
    const int row16 = lane & 15;                     // A row within the half-batch
    const int lc    = nh * 16 + (lane & 15);         // local col 0..31
    const int bswz  = (lc & 7) << 4;
    const char* Bw1 = W1s + lc * 2048;
    const char* Bw2 = W2s + lc * 2048;
    const float bias1 = b1[cb + lc];
    const float bias2 = b2[cb + lc];
    const int lrow0 = kgrp * 4;                      // local C/D row base (0..12)
    const int dcol  = cb + lc;
    const float P = 0.97f, OMP = 1.0f - 0.97f;

    // store-pass roles (tid < 128): row srow (0..15), 4 cols from scol
    const int srow = tid >> 3;
    const int scol = (tid & 7) * 4;

    // ---- slot bodies ----
    auto slot_p1 = [&](int half, int t, unsigned* fl) {
        const char* Ab = (const char*)sBuf +
            (size_t)(rb + half * RPH + row16) * 2048 + kboff + kbyte;
        f32x4 part = phase_mm_half(Ab, Bw1, kbyte, bswz, kboff);
        if (kh) {
            #pragma unroll
            for (int j = 0; j < 4; ++j) T[(lrow0 + j) * TSTR + lc] = part[j];
        }
        __syncthreads();
        if (!kh) {
            #pragma unroll
            for (int j = 0; j < 4; ++j) {
                const int idx = (lrow0 + j) * TSTR + lc;
                T[idx] = fabsf(part[j] + T[idx] + bias1);
            }
        }
        __syncthreads();
        if (tid < 128) {
            f32x4 hv = *reinterpret_cast<const f32x4*>(&T[srow * TSTR + scol]);
            const int grow = rb + half * RPH + srow;
            st_coh_b64(hBuf + (size_t)grow * SSZ + cb + scol, pack_bf16x4(hv));
        }
        publish_flags(fl, c, (unsigned)(2 + 2 * t), tid);
    };

    auto slot_p2 = [&](int half, int t, unsigned* fl,
                       float sp0, float sp1, float sp2, float sp3) {
        const char* Ab = (const char*)hBuf +
            (size_t)(rb + half * RPH + row16) * 2048 + kboff + kbyte;
        f32x4 part = phase_mm_half(Ab, Bw2, kbyte, bswz, kboff);
        if (kh) {
            #pragma unroll
            for (int j = 0; j < 4; ++j) T[(lrow0 + j) * TSTR + lc] = part[j];
        }
        __syncthreads();
        if (!kh) {
            const float spv[4] = {sp0, sp1, sp2, sp3};
            #pragma unroll
            for (int j = 0; j < 4; ++j) {
                const int idx = (lrow0 + j) * TSTR + lc;
                T[idx] = P * spv[j] + OMP * (part[j] + T[idx] + bias2);
            }
        }
        __syncthreads();
        if (tid < 128) {
            float* swr = sf32 + (size_t)((t + 1) & 1) * (BATCH * SSZ);
            f32x4 sv = *reinterpret_cast<const f32x4*>(&T[srow * TSTR + scol]);
            const int grow = rb + half * RPH + srow;
            st_coh_b128(&swr[(size_t)grow * SSZ + cb + scol], sv);
            if (c < 30) {
                st_coh_b64(sBuf + (size_t)grow * SSZ + (cb + 64) + scol, pack_bf16x4(sv));
            } else if (t == NSTEP - 1) {
                *reinterpret_cast<f32x4*>(&dout[grow * 64 + (cb - 960) + scol]) = sv;
            }
            if (c < 2 && t < NSTEP - 1) {
                f32x4 xv = *reinterpret_cast<const f32x4*>(
                    &x[(size_t)(t + 1) * (BATCH * INSZ) + (size_t)grow * INSZ + cb + scol]);
                st_coh_b64(sBuf + (size_t)grow * SSZ + cb + scol, pack_bf16x4(xv));
            }
        }
        publish_flags(fl, c, (unsigned)(3 + 2 * t), tid);
    };

    // residual-input prefetch for P2 of one half (kh==0 waves only)
    auto prefetch_sprev = [&](int half, int t,
                              float& sp0, float& sp1, float& sp2, float& sp3) {
        if (kh == 0) {
            const int grow0 = rb + half * RPH + lrow0;
            if (c < 2) {
                const float* xp = x + (size_t)t * (BATCH * INSZ);
                sp0 = xp[(size_t)(grow0 + 0) * INSZ + dcol];
                sp1 = xp[(size_t)(grow0 + 1) * INSZ + dcol];
                sp2 = xp[(size_t)(grow0 + 2) * INSZ + dcol];
                sp3 = xp[(size_t)(grow0 + 3) * INSZ + dcol];
            } else {
                const float* srd = sf32 + (size_t)(t & 1) * (BATCH * SSZ);
                issue4f(&srd[(size_t)(grow0 + 0) * SSZ + (dcol - 64)],
                        &srd[(size_t)(grow0 + 1) * SSZ + (dcol - 64)],
                        &srd[(size_t)(grow0 + 2) * SSZ + (dcol - 64)],
                        &srd[(size_t)(grow0 + 3) * SSZ + (dcol - 64)],
                        sp0, sp1, sp2, sp3);   // drained by phase_mm's vmcnt(0)
            }
        }
    };

    // ---- main loop: interleaved half-batch chains ----
    for (int t = 0; t < NSTEP; ++t) {
        slot_p1(0, t, flA);                                    // P1A, publish hA
        wait_flags(flB, (unsigned)(1 + 2 * t), tid);           // sB(t) ready
        slot_p1(1, t, flB);                                    // P1B, publish hB

        float a0, a1, a2, a3;
        prefetch_sprev(0, t, a0, a1, a2, a3);                  // rides the poll
        wait_flags(flA, (unsigned)(2 + 2 * t), tid);           // hA(t) ready
        slot_p2(0, t, flA, a0, a1, a2, a3);                    // P2A, publish sA

        float c0, c1, c2, c3;
        prefetch_sprev(1, t, c0, c1, c2, c3);
        wait_flags(flB, (unsigned)(2 + 2 * t), tid);           // hB(t) ready
        slot_p2(1, t, flB, c0, c1, c2, c3);                    // P2B, publish sB

        if (t < NSTEP - 1)
            wait_flags(flA, (unsigned)(3 + 2 * t), tid);       // sA(t+1) for next P1A
    }
}

extern "C" void kernel_launch(void* const* d_in, const int* in_sizes, int n_in,
                              void* d_out, int out_size, void* d_ws, size_t ws_size,
                              hipStream_t stream)
{
    const float* x  = (const float*)d_in[0];
    const float* W1 = (const float*)d_in[1];
    const float* b1 = (const float*)d_in[2];
    const float* W2 = (const float*)d_in[3];
    const float* b2 = (const float*)d_in[4];
    float* dout = (float*)d_out;

    char* ws = (char*)d_ws;
    __bf16*   sBuf  = (__bf16*)(ws);                 // 512 KiB: shifted s_t, bf16
    __bf16*   hBuf  = (__bf16*)(ws + (512 << 10));   // 512 KiB: h, bf16
    float*    sf32  = (float*)(ws + (1 << 20));      // 2 MiB: fp32 S ping-pong
    unsigned* flags = (unsigned*)(ws + (3 << 20));   // 32 KiB: 2 chains x 8 groups x 32

    (void)in_sizes; (void)n_in; (void)out_size; (void)ws_size;

    (void)hipFuncSetAttribute(reinterpret_cast<const void*>(&resrnn_kernel),
                              hipFuncAttributeMaxDynamicSharedMemorySize, 133376);
    hipLaunchKernelGGL(resrnn_kernel, dim3(256), dim3(256), 133376, stream,
                       x, W1, b1, W2, b2, sBuf, hBuf, sf32, flags, dout);
}